// Round 21
// baseline (151.126 us; speedup 1.0000x reference)
//
#include <hip/hip_runtime.h>
#include <math.h>

#define KNN 16
#define NPTS 8192
#define PTCH 256
#define NPATCH 32
#define NBATCH 4
#define SSTRIDE 130      // survivor slots per HALF-query region
#define LAMBDA_T 48.0f   // target E[survivors]/query

// radial gate table
#define GTAB 512
#define RMAX 6.5f
#define GH (RMAX / (float)GTAB)

// spatial grid
#define NC 16
#define NCELLS (NC * NC * NC)
#define GMIN -4.2f
#define ICS 1.9047619f   // 1 / 0.525 ; NC*0.525 = 8.4 spans [-4.2, 4.2]

// E[#points within distance s of a query at radius r], N iid N(0,I3). fp32.
// Heuristic only: exactness guaranteed by margin check + fallback.
__device__ __forceinline__ float lam_f(float r, float s)
{
    const float C     = 0.063493636f;    // (2*pi)^{-3/2}
    const float SQ2PI = 2.5066283f;
    const float IS2   = 0.70710678f;
    float a = fabsf(r - s), b = r + s;
    float amr = a - r;
    float coefA = amr * amr + 2.f - s * s;
    float I = 2.f * __expf(-0.5f * b * b) - coefA * __expf(-0.5f * a * a)
            + r * SQ2PI * (erff(b * IS2) - erff(a * IS2));
    float M = C * (3.14159265f / r) * I;
    if (s > r) {
        float u = s - r;
        M += 12.566371f * C * (1.2533141f * erff(u * IS2) - u * __expf(-0.5f * u * u));
    }
    return (float)NPTS * M;
}

// ---------- fp64 cyclic Jacobi 3x3 (verified) ----------
__device__ __forceinline__ void jrot(double& app, double& aqq, double& apq,
                                     double& arp, double& arq,
                                     double& vp0, double& vq0,
                                     double& vp1, double& vq1,
                                     double& vp2, double& vq2)
{
    double g = apq;
    if (g == 0.0) return;
    double theta = (aqq - app) / (2.0 * g);
    double at = fabs(theta);
    double t = (at > 1.0e154) ? (0.5 / theta)
                              : (copysign(1.0, theta) / (at + sqrt(theta * theta + 1.0)));
    double c = 1.0 / sqrt(t * t + 1.0);
    double s = t * c;
    double tau = s / (1.0 + c);
    app -= t * g;
    aqq += t * g;
    apq = 0.0;
    double rp = arp, rq = arq;
    arp = rp - s * (rq + tau * rp);
    arq = rq + s * (rp - tau * rq);
    double p0 = vp0, q0 = vq0;
    vp0 = p0 - s * (q0 + tau * p0); vq0 = q0 + s * (p0 - tau * q0);
    double p1 = vp1, q1 = vq1;
    vp1 = p1 - s * (q1 + tau * p1); vq1 = q1 + s * (p1 - tau * q1);
    double p2 = vp2, q2 = vq2;
    vp2 = p2 - s * (q2 + tau * p2); vq2 = q2 + s * (p2 - tau * q2);
}

__device__ __forceinline__ void eig3(double a00, double a11, double a22,
                                     double a01, double a02, double a12,
                                     double& nx, double& ny, double& nz,
                                     double& lmin, double& lsum)
{
    double v00 = 1, v01 = 0, v02 = 0;
    double v10 = 0, v11 = 1, v12 = 0;
    double v20 = 0, v21 = 0, v22 = 1;
    double scale = fabs(a00) + fabs(a11) + fabs(a22) + fabs(a01) + fabs(a02) + fabs(a12);
    if (scale > 0.0) {
        for (int sweep = 0; sweep < 6; ++sweep) {
            double off = fabs(a01) + fabs(a02) + fabs(a12);
            if (off <= scale * 1e-15) break;
            jrot(a00, a11, a01, a02, a12, v00, v01, v10, v11, v20, v21);
            jrot(a00, a22, a02, a01, a12, v00, v02, v10, v12, v20, v22);
            jrot(a11, a22, a12, a01, a02, v01, v02, v11, v12, v21, v22);
        }
    }
    lsum = a00 + a11 + a22;
    lmin = a00; nx = v00; ny = v10; nz = v20;
    if (a11 < lmin) { lmin = a11; nx = v01; ny = v11; nz = v21; }
    if (a22 < lmin) { lmin = a22; nx = v02; ny = v12; nz = v22; }
}

// u32 key: (d2 float bits, low 13 mantissa bits cleared) | idx(13b). Ties -> lower idx.
__device__ __forceinline__ unsigned mkkey(float d2, unsigned idx) {
    return (__float_as_uint(d2) & 0xFFFFE000u) | idx;
}

// Caller guarantees key < L[15]. Sorted-ascending bubble (v_min/v_max pairs).
__device__ __forceinline__ void insert16(unsigned key, unsigned* L)
{
    L[KNN - 1] = key;
    #pragma unroll
    for (int m = KNN - 1; m >= 1; --m) {
        unsigned a = L[m - 1], b = L[m];
        L[m - 1] = min(a, b);
        L[m]     = max(a, b);
    }
}

// Snapshot-based butterfly merge of sorted 16-lists across lanes h = lane&3.
__device__ __forceinline__ void merge4(unsigned* L, int lane)
{
    #pragma unroll
    for (int step = 1; step <= 2; step <<= 1) {
        unsigned tmp[KNN];
        #pragma unroll
        for (int m = 0; m < KNN; ++m) tmp[m] = __shfl(L[m], lane ^ step, 64);
        for (int m = 0; m < KNN; ++m) {
            if (tmp[m] >= L[KNN - 1]) break;
            insert16(tmp[m], L);
        }
    }
}

__device__ __forceinline__ unsigned mbcnt64(unsigned long long m) {
    return __builtin_amdgcn_mbcnt_hi((unsigned)(m >> 32),
           __builtin_amdgcn_mbcnt_lo((unsigned)m, 0u));
}

// ---------- grid build ----------
__device__ __forceinline__ int cidx(float v) {
    int i = (int)floorf((v - GMIN) * ICS);
    return min(max(i, 0), NC - 1);
}
__device__ __forceinline__ int cellOf(float x, float y, float z) {
    return (cidx(z) * NC + cidx(y)) * NC + cidx(x);
}

// One block per batch: histogram + scan + scatter, all in LDS. Block 0 also
// fills the radial gate table and zeroes the eig completion counter.
#define BT 1024
__global__ void __launch_bounds__(1024)
build_kernel(const float* __restrict__ pts,
             unsigned* __restrict__ cellStart, float4* __restrict__ sorted,
             float* __restrict__ gtab, unsigned* __restrict__ done)
{
    __shared__ unsigned hist[NCELLS];     // 16 KB; reused as cellPos after scan
    __shared__ unsigned part[BT];         // 4 KB
    const int b = blockIdx.x;
    const int t = threadIdx.x;
    if (b == 0 && t == 0) done[0] = 0u;
    for (int i = t; i < NCELLS; i += BT) hist[i] = 0u;
    __syncthreads();
    const float* base = pts + (size_t)b * (NPTS * 3);
    float px[8], py[8], pz[8];
    int pc[8];
    #pragma unroll
    for (int k = 0; k < 8; ++k) {
        int i = k * BT + t;
        px[k] = base[i * 3 + 0];
        py[k] = base[i * 3 + 1];
        pz[k] = base[i * 3 + 2];
        pc[k] = cellOf(px[k], py[k], pz[k]);
        atomicAdd(&hist[pc[k]], 1u);
    }
    __syncthreads();
    // scan: thread t owns cells t*4 .. t*4+3
    unsigned loc[4], s = 0;
    #pragma unroll
    for (int i = 0; i < 4; ++i) { loc[i] = s; s += hist[t * 4 + i]; }
    part[t] = s;
    __syncthreads();
    for (int o = 1; o < BT; o <<= 1) {
        unsigned u = (t >= o) ? part[t - o] : 0u;
        __syncthreads();
        part[t] += u;
        __syncthreads();
    }
    unsigned basex = part[t] - s;   // exclusive prefix of this thread's 4-cell chunk
    unsigned* csb = cellStart + b * (NCELLS + 1);
    #pragma unroll
    for (int i = 0; i < 4; ++i) {
        unsigned e = basex + loc[i];
        csb[t * 4 + i] = e;
        hist[t * 4 + i] = e;        // becomes running cell position
    }
    if (t == BT - 1) csb[NCELLS] = basex + s;   // == NPTS
    __syncthreads();
    float4* sb = sorted + (size_t)b * NPTS;
    #pragma unroll
    for (int k = 0; k < 8; ++k) {
        int i = k * BT + t;
        unsigned slot = atomicAdd(&hist[pc[k]], 1u);
        float4 v;
        v.x = px[k]; v.y = py[k]; v.z = pz[k]; v.w = __uint_as_float((unsigned)i);
        sb[slot] = v;
    }
    // radial gate table: entry i = 16-step bisection at the bin's UPPER edge
    // r=(i+1)*GH. g increasing in r -> g(r_hi) >= g(r): conservative gate.
    if (b == 0 && t < GTAB) {
        float r = fmaxf((float)(t + 1) * GH, 0.01f);
        float lo = 0.f, hi = 12.f;
        #pragma unroll 1
        for (int it = 0; it < 16; ++it) {
            float mid = 0.5f * (lo + hi);
            if (lam_f(r, mid) < LAMBDA_T) lo = mid; else hi = mid;
        }
        gtab[t] = hi;
    }
}

// Fused filter+select, R21: TWO WAVES PER QUERY. Wave A streams rows
// [0, ceil(nyz/2)), wave B the rest, each into its own 130-slot LDS region
// (halving the per-query serial chain -- the measured wall is ~2x issue).
// After __syncthreads, the primary wave compacts B's region behind A's
// (disjoint, parallel copy) and runs the VERBATIM rank-select / margin /
// fallback on the combined keys. Survivor multiset = exact union of halves
// = the old set; rank-select is value-ordered -> idx16 bit-identical.
// Block = 4 waves = 2 queries; grid 16384.
__global__ void __launch_bounds__(256)
fselect_kernel(const float* __restrict__ pts,
               const unsigned* __restrict__ cellStart,
               const float4* __restrict__ sortedp,
               const float* __restrict__ gtab,
               unsigned* __restrict__ idx16)
{
    __shared__ unsigned survl[2 * 2 * SSTRIDE];   // 2 queries x 2 regions
    __shared__ unsigned scnt[4];
    const int t = threadIdx.x;
    const int wv = t >> 6;
    const int lane = t & 63;
    const int qw = wv >> 1;                   // query within block: 0..1
    const int sh = wv & 1;                    // sub-wave: 0 = rows lo, 1 = rows hi
    const int wq = __builtin_amdgcn_readfirstlane(blockIdx.x * 2 + qw);
    const int b   = wq >> 13;
    const int pos = wq & (NPTS - 1);          // position in cell-sorted array
    const float* base = pts + (size_t)b * (NPTS * 3);
    const unsigned* cs = cellStart + b * (NCELLS + 1);
    const float4* sp = sortedp + (size_t)b * NPTS;
    unsigned* sl = survl + qw * (2 * SSTRIDE);   // this query's combined buffer

    const float4 qc = sp[pos];                // wave-uniform (broadcast load)
    const float qx = qc.x, qy = qc.y, qz = qc.z;
    const int oq = b * NPTS + (int)__float_as_uint(qc.w);   // ORIGINAL query id

    // ---- gate: radial table lookup (bin upper-edge g, conservative) ----
    const float r = sqrtf(qx * qx + qy * qy + qz * qz);
    const int gi = min(GTAB - 1, (int)(r * (1.0f / GH)));
    const float g = gtab[gi];
    const float g2 = g * g;

    int ixlo = cidx(qx - g), ixhi = cidx(qx + g);
    int iylo = cidx(qy - g), iyhi = cidx(qy + g);
    int izlo = cidx(qz - g), izhi = cidx(qz + g);
    int nx = ixhi - ixlo + 1;
    int ny = iyhi - iylo + 1;
    int nyz = ny * (izhi - izlo + 1);
    const int lR  = (nyz >= 8) ? 3 : (nyz >= 4) ? 2 : (nyz >= 2) ? 1 : 0;
    const int R   = 1 << lR;
    const int lsl = 6 - lR;
    const unsigned SL = 64u >> lR;
    const unsigned slot = (unsigned)lane & (SL - 1u);
    // this sub-wave's row range
    const int half = (nyz + 1) >> 1;
    const int rlo = sh ? half : 0;
    const int rhi = sh ? nyz : half;
    unsigned* myr = sl + sh * SSTRIDE;        // my survivor region
    unsigned cnt = 0;                          // wave-uniform by construction
    #pragma unroll 1
    for (int r0 = rlo; r0 < rhi; r0 += 64) {
        int rr = r0 + lane;
        unsigned pk = 0;
        if (rr < rhi) {
            int iz = izlo + rr / ny;
            int iy = iylo + (rr - (rr / ny) * ny);
            int cb = (iz * NC + iy) * NC + ixlo;
            unsigned sB = cs[cb];
            pk = sB | ((cs[cb + nx] - sB) << 14);
        }
        int rmax = min(rhi - r0, 64);
        int gcount = (rmax + R - 1) >> lR;
        #pragma unroll 1
        for (int gg = 0; gg < gcount; ++gg) {
            unsigned pkm = __shfl(pk, (gg << lR) + (lane >> lsl), 64);
            unsigned sBm = pkm & 0x3FFFu;
            unsigned lm  = pkm >> 14;
            #pragma unroll 1
            for (unsigned st = slot; ; st += 2u * SL) {
                bool in0 = st < lm;
                if (!__any(in0 ? 1 : 0)) break;   // st>=lm all lanes => st+SL too
                unsigned st1 = st + SL;
                bool in1 = st1 < lm;
                float4 c0 = sp[min(sBm + st,  (unsigned)(NPTS - 1))];
                float4 c1 = sp[min(sBm + st1, (unsigned)(NPTS - 1))];
                float dx0 = qx - c0.x, dy0 = qy - c0.y, dz0 = qz - c0.z;
                float d20 = dx0 * dx0 + dy0 * dy0 + dz0 * dz0;
                float dx1 = qx - c1.x, dy1 = qy - c1.y, dz1 = qz - c1.z;
                float d21 = dx1 * dx1 + dy1 * dy1 + dz1 * dz1;
                bool p0 = in0 && (d20 < g2);
                bool p1 = in1 && (d21 < g2);
                unsigned long long m0 = __ballot(p0);
                unsigned long long m1 = __ballot(p1);
                if (p0) {
                    unsigned sw = min(cnt + mbcnt64(m0), (unsigned)(SSTRIDE - 1));
                    myr[sw] = mkkey(d20, __float_as_uint(c0.w));
                }
                unsigned cn = cnt + (unsigned)__popcll(m0);
                if (p1) {
                    unsigned sw = min(cn + mbcnt64(m1), (unsigned)(SSTRIDE - 1));
                    myr[sw] = mkkey(d21, __float_as_uint(c1.w));
                }
                cnt = cn + (unsigned)__popcll(m1);
            }
        }
    }
    if (lane == 0) scnt[wv] = cnt;
    __syncthreads();
    if (sh != 0) return;                      // secondary wave done

    // ---- merge: compact region B behind region A (disjoint, parallel) ----
    unsigned cnt0 = scnt[qw * 2];
    unsigned cnt1 = scnt[qw * 2 + 1];
    cnt = cnt0 + cnt1;
    bool valid = (cnt >= KNN) && (cnt <= 128u);   // 2 keys/lane max
    if (valid) {
        // targets [cnt0, cnt) < 128 < 130 <= sources [130, 130+cnt1): no overlap
        for (unsigned i = lane; i < cnt1; i += 64) sl[cnt0 + i] = sl[SSTRIDE + i];
        // (wave-internal: same wave reads below, no barrier needed)
        unsigned k0 = (lane < (int)cnt)      ? sl[lane]      : 0xFFFFFFFFu;
        unsigned k1 = (lane + 64 < (int)cnt) ? sl[lane + 64] : 0xFFFFFFFFu;
        unsigned r0 = 0, r1 = 0;
        #pragma unroll 4
        for (unsigned m = 0; m < cnt; ++m) {
            unsigned km = sl[m];              // LDS broadcast (no conflict)
            r0 += (km < k0) ? 1u : 0u;
            r1 += (km < k1) ? 1u : 0u;
        }
        // P = 16th smallest = the key with rank 15 (exactly one; keys distinct)
        unsigned cand = 0;
        if (lane < (int)cnt && r0 == 15u) cand = k0;
        if (lane + 64 < (int)cnt && r1 == 15u) cand = k1;
        #pragma unroll
        for (int o = 1; o < 64; o <<= 1)
            cand = max(cand, (unsigned)__shfl_xor((int)cand, o, 64));
        // margin check: all filtered-out points provably outside 16th bucket
        float upper = __uint_as_float((cand & 0xFFFFE000u) + 0x2000u);
        valid = (upper < g2 * 0.999f - 1e-5f);
        if (valid) {
            if (lane < (int)cnt && r0 < 16u)
                idx16[(size_t)oq * 32 + r0] = k0 & 0x1FFFu;       // ascending
            if (lane + 64 < (int)cnt && r1 < 16u)
                idx16[(size_t)oq * 32 + r1] = k1 & 0x1FFFu;
        }
    }
    if (!valid && lane == 0) {       // exact fallback
        unsigned gl[KNN];
        #pragma unroll
        for (int m = 0; m < KNN; ++m) gl[m] = 0xFFFFFFFFu;
        #pragma unroll 1
        for (int i = 0; i < NPTS; ++i) {
            float cx = base[i * 3 + 0];
            float cy = base[i * 3 + 1];
            float cz = base[i * 3 + 2];
            float dx = qx - cx, dy = qy - cy, dz = qz - cz;
            float d2 = dx * dx + dy * dy + dz * dz;
            unsigned k = mkkey(d2, (unsigned)i);
            if (k < gl[KNN - 1]) insert16(k, gl);
        }
        unsigned* dst = idx16 + (size_t)oq * 32;
        #pragma unroll
        for (int m = 0; m < KNN; ++m) dst[m] = gl[m] & 0x1FFFu;
    }
}

// Patch kNN: 64 queries/block (quarter patch), 4 lanes/query x 64 patch pts,
// gated bubble insert + butterfly merge4 (verbatim, separate kernel).
__global__ void __launch_bounds__(256)
pselect_kernel(const float* __restrict__ pts, unsigned* __restrict__ idx16)
{
    __shared__ float4 pbuf4[PTCH];                 // 4 KB own patch
    const int t = threadIdx.x;
    const int w = t >> 6;
    const int lane = t & 63;
    const int p = blockIdx.x;
    const int quarter = blockIdx.y;
    const int b = blockIdx.z;
    const float* base = pts + (size_t)b * (NPTS * 3);

    {
        const float* src = base + p * (PTCH * 3);
        float* dst = (float*)pbuf4;
        #pragma unroll
        for (int s = 0; s < 3; ++s) {
            int f = t + s * 256;
            int j = f / 3;
            int c = f - 3 * j;
            dst[j * 4 + c] = src[f];
        }
    }
    __syncthreads();

    const int qq = lane >> 2;            // 0..15
    const int h = lane & 3;
    const int qlocal = quarter * 64 + w * 16 + qq;   // 0..255 within patch
    float4 qv = pbuf4[qlocal];
    const float pqx = qv.x, pqy = qv.y, pqz = qv.z;

    unsigned pl[KNN];
    #pragma unroll
    for (int m = 0; m < KNN; ++m) pl[m] = 0xFFFFFFFFu;
    const int j0 = h * 64;
    #pragma unroll 4
    for (int j = j0; j < j0 + 64; ++j) {
        float4 c = pbuf4[j];
        float dx = pqx - c.x, dy = pqy - c.y, dz = pqz - c.z;
        float d2 = dx * dx + dy * dy + dz * dz;
        unsigned k = mkkey(d2, (unsigned)j);
        if (k < pl[KNN - 1]) insert16(k, pl);
    }
    merge4(pl, lane);
    if (h == 0) {
        int qid = b * NPTS + p * PTCH + qlocal;
        unsigned* dst = idx16 + (size_t)qid * 32 + 16;   // type 1 = patch
        #pragma unroll
        for (int m = 0; m < KNN; ++m)
            dst[m] = (unsigned)(p * PTCH) + (pl[m] & 0x1FFFu);
    }
}

// 1 thread per eig (65536); full-lane fp64. Last-finishing block performs the
// (identical, fixed-order) final reduction -- absorbs the reduce launch.
__global__ void __launch_bounds__(256)
eig_loss_kernel(const float* __restrict__ pts,
                const unsigned* __restrict__ idx16,
                double* __restrict__ partials,
                unsigned* __restrict__ done,
                float* __restrict__ out)
{
    __shared__ double sln[4], slv[4];
    __shared__ unsigned isLast;
    const int t = threadIdx.x;
    const int e = blockIdx.x * 256 + t;     // 0..65535
    const int qid = e >> 1;
    const int b = qid >> 13;
    const int qi = qid & (NPTS - 1);
    const float* base = pts + (size_t)b * (NPTS * 3);

    const double qxd = (double)base[qi * 3 + 0];
    const double qyd = (double)base[qi * 3 + 1];
    const double qzd = (double)base[qi * 3 + 2];

    const unsigned* L = idx16 + (size_t)qid * 32 + (e & 1) * 16;
    double c00 = 0, c11 = 0, c22 = 0, c01 = 0, c02 = 0, c12 = 0;
    #pragma unroll
    for (int m = 0; m < KNN; ++m) {
        int idx = (int)L[m];
        double dx = (double)base[idx * 3 + 0] - qxd;
        double dy = (double)base[idx * 3 + 1] - qyd;
        double dz = (double)base[idx * 3 + 2] - qzd;
        c00 += dx * dx; c11 += dy * dy; c22 += dz * dz;
        c01 += dx * dy; c02 += dx * dz; c12 += dy * dz;
    }
    double nx, ny, nz, lmin, lsum;
    eig3(c00, c11, c22, c01, c02, c12, nx, ny, nz, lmin, lsum);
    double sv = lmin / lsum;

    double onx = __shfl_xor(nx, 1, 64);
    double ony = __shfl_xor(ny, 1, 64);
    double onz = __shfl_xor(nz, 1, 64);
    double osv = __shfl_xor(sv, 1, 64);

    double ln = 0.0, lsv = 0.0;
    if ((e & 1) == 0) {          // even lane: own = global, partner = patch
        double dx = fabs(onx) - fabs(nx);
        double dy = fabs(ony) - fabs(ny);
        double dz = fabs(onz) - fabs(nz);
        ln  = sqrt(dx * dx + dy * dy + dz * dz);
        double ds = osv - sv;
        lsv = ds * ds;
    }
    #pragma unroll
    for (int o = 32; o > 0; o >>= 1) {
        ln  += __shfl_down(ln, o);
        lsv += __shfl_down(lsv, o);
    }
    const int w = t >> 6;
    if ((t & 63) == 0) { sln[w] = ln; slv[w] = lsv; }
    __syncthreads();
    if (t == 0) {
        partials[blockIdx.x * 2 + 0] = sln[0] + sln[1] + sln[2] + sln[3];
        partials[blockIdx.x * 2 + 1] = slv[0] + slv[1] + slv[2] + slv[3];
        __threadfence();
        isLast = (atomicAdd(done, 1u) == (unsigned)(gridDim.x - 1)) ? 1u : 0u;
    }
    __syncthreads();
    if (isLast) {
        // identical fixed-order 256-pair reduction (former reduce_kernel)
        double a = partials[t * 2 + 0];
        double c = partials[t * 2 + 1];
        #pragma unroll
        for (int o = 32; o > 0; o >>= 1) {
            a += __shfl_down(a, o);
            c += __shfl_down(c, o);
        }
        if ((t & 63) == 0) { sln[t >> 6] = a; slv[t >> 6] = c; }
        __syncthreads();
        if (t == 0) {
            const double inv = 1.0 / (double)(NBATCH * NPTS);
            out[0] = (float)((sln[0] + sln[1] + sln[2] + sln[3]) * inv);
            out[1] = (float)((slv[0] + slv[1] + slv[2] + slv[3]) * inv);
        }
    }
}

extern "C" void kernel_launch(void* const* d_in, const int* in_sizes, int n_in,
                              void* d_out, int out_size, void* d_ws, size_t ws_size,
                              hipStream_t stream)
{
    const float* pts = (const float*)d_in[0];
    float* out = (float*)d_out;

    // workspace carve-up (16B-aligned), ~4.8 MB total:
    //   cellStart @ 0       : 4*4097*4   = 65552
    //   sorted    @ 65552   : 4*8192*16  = 524288  -> 589840
    //   gtab      @ 589840  : 512*4      = 2048    -> 591888
    //   done      @ 591888  : 16         = 16      -> 591904
    //   idx16     @ 591904  : 32768*32*4 = 4194304 -> 4786208
    //   partials  @ 4786208 : 256*2*8    = 4096    -> 4790304
    unsigned char* ws = (unsigned char*)d_ws;
    unsigned* cellStart = (unsigned*)(ws);
    float4*   sorted    = (float4*)  (ws + 65552);
    float*    gtab      = (float*)   (ws + 589840);
    unsigned* done      = (unsigned*)(ws + 591888);
    unsigned* idx16     = (unsigned*)(ws + 591904);
    double*   partials  = (double*)  (ws + 4786208);

    hipLaunchKernelGGL(build_kernel, dim3(NBATCH), dim3(BT), 0, stream,
                       pts, cellStart, sorted, gtab, done);
    hipLaunchKernelGGL(fselect_kernel, dim3(NBATCH * NPTS / 2), dim3(256), 0, stream,
                       pts, cellStart, sorted, gtab, idx16);
    hipLaunchKernelGGL(pselect_kernel, dim3(NPATCH, 4, NBATCH), dim3(256), 0, stream,
                       pts, idx16);
    hipLaunchKernelGGL(eig_loss_kernel, dim3(NBATCH * NPTS * 2 / 256), dim3(256),
                       0, stream, pts, idx16, partials, done, out);
}

// Round 22
// 136.008 us; speedup vs baseline: 1.1112x; 1.1112x over previous
//
#include <hip/hip_runtime.h>
#include <math.h>

#define KNN 16
#define NPTS 8192
#define PTCH 256
#define NPATCH 32
#define NBATCH 4
#define SSTRIDE 130      // survivor slots/query
#define LAMBDA_T 48.0f   // target E[survivors]/query

// radial gate table
#define GTAB 512
#define RMAX 6.5f
#define GH (RMAX / (float)GTAB)

// spatial grid
#define NC 16
#define NCELLS (NC * NC * NC)
#define GMIN -4.2f
#define ICS 1.9047619f   // 1 / 0.525 ; NC*0.525 = 8.4 spans [-4.2, 4.2]

// E[#points within distance s of a query at radius r], N iid N(0,I3). fp32.
// Heuristic only: exactness guaranteed by margin check + fallback.
__device__ __forceinline__ float lam_f(float r, float s)
{
    const float C     = 0.063493636f;    // (2*pi)^{-3/2}
    const float SQ2PI = 2.5066283f;
    const float IS2   = 0.70710678f;
    float a = fabsf(r - s), b = r + s;
    float amr = a - r;
    float coefA = amr * amr + 2.f - s * s;
    float I = 2.f * __expf(-0.5f * b * b) - coefA * __expf(-0.5f * a * a)
            + r * SQ2PI * (erff(b * IS2) - erff(a * IS2));
    float M = C * (3.14159265f / r) * I;
    if (s > r) {
        float u = s - r;
        M += 12.566371f * C * (1.2533141f * erff(u * IS2) - u * __expf(-0.5f * u * u));
    }
    return (float)NPTS * M;
}

// ---------- fp64 cyclic Jacobi 3x3 (verified) ----------
__device__ __forceinline__ void jrot(double& app, double& aqq, double& apq,
                                     double& arp, double& arq,
                                     double& vp0, double& vq0,
                                     double& vp1, double& vq1,
                                     double& vp2, double& vq2)
{
    double g = apq;
    if (g == 0.0) return;
    double theta = (aqq - app) / (2.0 * g);
    double at = fabs(theta);
    double t = (at > 1.0e154) ? (0.5 / theta)
                              : (copysign(1.0, theta) / (at + sqrt(theta * theta + 1.0)));
    double c = 1.0 / sqrt(t * t + 1.0);
    double s = t * c;
    double tau = s / (1.0 + c);
    app -= t * g;
    aqq += t * g;
    apq = 0.0;
    double rp = arp, rq = arq;
    arp = rp - s * (rq + tau * rp);
    arq = rq + s * (rp - tau * rq);
    double p0 = vp0, q0 = vq0;
    vp0 = p0 - s * (q0 + tau * p0); vq0 = q0 + s * (p0 - tau * q0);
    double p1 = vp1, q1 = vq1;
    vp1 = p1 - s * (q1 + tau * p1); vq1 = q1 + s * (p1 - tau * q1);
    double p2 = vp2, q2 = vq2;
    vp2 = p2 - s * (q2 + tau * p2); vq2 = q2 + s * (p2 - tau * q2);
}

__device__ __forceinline__ void eig3(double a00, double a11, double a22,
                                     double a01, double a02, double a12,
                                     double& nx, double& ny, double& nz,
                                     double& lmin, double& lsum)
{
    double v00 = 1, v01 = 0, v02 = 0;
    double v10 = 0, v11 = 1, v12 = 0;
    double v20 = 0, v21 = 0, v22 = 1;
    double scale = fabs(a00) + fabs(a11) + fabs(a22) + fabs(a01) + fabs(a02) + fabs(a12);
    if (scale > 0.0) {
        for (int sweep = 0; sweep < 6; ++sweep) {
            double off = fabs(a01) + fabs(a02) + fabs(a12);
            if (off <= scale * 1e-15) break;
            jrot(a00, a11, a01, a02, a12, v00, v01, v10, v11, v20, v21);
            jrot(a00, a22, a02, a01, a12, v00, v02, v10, v12, v20, v22);
            jrot(a11, a22, a12, a01, a02, v01, v02, v11, v12, v21, v22);
        }
    }
    lsum = a00 + a11 + a22;
    lmin = a00; nx = v00; ny = v10; nz = v20;
    if (a11 < lmin) { lmin = a11; nx = v01; ny = v11; nz = v21; }
    if (a22 < lmin) { lmin = a22; nx = v02; ny = v12; nz = v22; }
}

// u32 key: (d2 float bits, low 13 mantissa bits cleared) | idx(13b). Ties -> lower idx.
__device__ __forceinline__ unsigned mkkey(float d2, unsigned idx) {
    return (__float_as_uint(d2) & 0xFFFFE000u) | idx;
}

// Caller guarantees key < L[15]. Sorted-ascending bubble (v_min/v_max pairs).
__device__ __forceinline__ void insert16(unsigned key, unsigned* L)
{
    L[KNN - 1] = key;
    #pragma unroll
    for (int m = KNN - 1; m >= 1; --m) {
        unsigned a = L[m - 1], b = L[m];
        L[m - 1] = min(a, b);
        L[m]     = max(a, b);
    }
}

// Snapshot-based butterfly merge of sorted 16-lists across lanes h = lane&3.
__device__ __forceinline__ void merge4(unsigned* L, int lane)
{
    #pragma unroll
    for (int step = 1; step <= 2; step <<= 1) {
        unsigned tmp[KNN];
        #pragma unroll
        for (int m = 0; m < KNN; ++m) tmp[m] = __shfl(L[m], lane ^ step, 64);
        for (int m = 0; m < KNN; ++m) {
            if (tmp[m] >= L[KNN - 1]) break;
            insert16(tmp[m], L);
        }
    }
}

__device__ __forceinline__ unsigned mbcnt64(unsigned long long m) {
    return __builtin_amdgcn_mbcnt_hi((unsigned)(m >> 32),
           __builtin_amdgcn_mbcnt_lo((unsigned)m, 0u));
}

// ---------- grid build ----------
__device__ __forceinline__ int cidx(float v) {
    int i = (int)floorf((v - GMIN) * ICS);
    return min(max(i, 0), NC - 1);
}
__device__ __forceinline__ int cellOf(float x, float y, float z) {
    return (cidx(z) * NC + cidx(y)) * NC + cidx(x);
}

// One block per batch: histogram + scan + scatter, all in LDS. Block 0 also
// fills the radial gate table (512 x 16-step bisection = 8k lam_f total).
#define BT 1024
__global__ void __launch_bounds__(1024)
build_kernel(const float* __restrict__ pts,
             unsigned* __restrict__ cellStart, float4* __restrict__ sorted,
             float* __restrict__ gtab)
{
    __shared__ unsigned hist[NCELLS];     // 16 KB; reused as cellPos after scan
    __shared__ unsigned part[BT];         // 4 KB
    const int b = blockIdx.x;
    const int t = threadIdx.x;
    for (int i = t; i < NCELLS; i += BT) hist[i] = 0u;
    __syncthreads();
    const float* base = pts + (size_t)b * (NPTS * 3);
    float px[8], py[8], pz[8];
    int pc[8];
    #pragma unroll
    for (int k = 0; k < 8; ++k) {
        int i = k * BT + t;
        px[k] = base[i * 3 + 0];
        py[k] = base[i * 3 + 1];
        pz[k] = base[i * 3 + 2];
        pc[k] = cellOf(px[k], py[k], pz[k]);
        atomicAdd(&hist[pc[k]], 1u);
    }
    __syncthreads();
    // scan: thread t owns cells t*4 .. t*4+3
    unsigned loc[4], s = 0;
    #pragma unroll
    for (int i = 0; i < 4; ++i) { loc[i] = s; s += hist[t * 4 + i]; }
    part[t] = s;
    __syncthreads();
    for (int o = 1; o < BT; o <<= 1) {
        unsigned u = (t >= o) ? part[t - o] : 0u;
        __syncthreads();
        part[t] += u;
        __syncthreads();
    }
    unsigned basex = part[t] - s;   // exclusive prefix of this thread's 4-cell chunk
    unsigned* csb = cellStart + b * (NCELLS + 1);
    #pragma unroll
    for (int i = 0; i < 4; ++i) {
        unsigned e = basex + loc[i];
        csb[t * 4 + i] = e;
        hist[t * 4 + i] = e;        // becomes running cell position
    }
    if (t == BT - 1) csb[NCELLS] = basex + s;   // == NPTS
    __syncthreads();
    float4* sb = sorted + (size_t)b * NPTS;
    #pragma unroll
    for (int k = 0; k < 8; ++k) {
        int i = k * BT + t;
        unsigned slot = atomicAdd(&hist[pc[k]], 1u);
        float4 v;
        v.x = px[k]; v.y = py[k]; v.z = pz[k]; v.w = __uint_as_float((unsigned)i);
        sb[slot] = v;
    }
    // radial gate table: entry i = 16-step bisection at the bin's UPPER edge
    // r=(i+1)*GH. g increasing in r -> g(r_hi) >= g(r): conservative gate.
    if (b == 0 && t < GTAB) {
        float r = fmaxf((float)(t + 1) * GH, 0.01f);
        float lo = 0.f, hi = 12.f;
        #pragma unroll 1
        for (int it = 0; it < 16; ++it) {
            float mid = 0.5f * (lo + hi);
            if (lam_f(r, mid) < LAMBDA_T) lo = mid; else hi = mid;
        }
        gtab[t] = hi;
    }
}

// Fused filter+select (R17-verified best: 46.3us, VGPR 16, LDS 2560,
// occupancy 54%). One WAVE per query, cell-major order. Table gate,
// 2x-unrolled candidate stream, LDS rank-select, margin + exact fallback.
// R21's 2-wave-per-query split REGRESSED (58.6us: duplicated per-group
// issue overhead on an already ~2/3-issue-bound kernel); reverted.
__global__ void __launch_bounds__(256)
fselect_kernel(const float* __restrict__ pts,
               const unsigned* __restrict__ cellStart,
               const float4* __restrict__ sortedp,
               const float* __restrict__ gtab,
               unsigned* __restrict__ idx16)
{
    __shared__ unsigned survl[4 * SSTRIDE];   // 2 KB: 4 queries/block
    const int t = threadIdx.x;
    const int wv = t >> 6;
    const int lane = t & 63;
    const int wq = __builtin_amdgcn_readfirstlane(blockIdx.x * 4 + wv);
    const int b   = wq >> 13;
    const int pos = wq & (NPTS - 1);          // position in cell-sorted array
    const float* base = pts + (size_t)b * (NPTS * 3);
    const unsigned* cs = cellStart + b * (NCELLS + 1);
    const float4* sp = sortedp + (size_t)b * NPTS;
    unsigned* sl = survl + wv * SSTRIDE;

    const float4 qc = sp[pos];                // wave-uniform (broadcast load)
    const float qx = qc.x, qy = qc.y, qz = qc.z;
    const int oq = b * NPTS + (int)__float_as_uint(qc.w);   // ORIGINAL query id

    // ---- gate: radial table lookup (bin upper-edge g, conservative) ----
    const float r = sqrtf(qx * qx + qy * qy + qz * qz);
    const int gi = min(GTAB - 1, (int)(r * (1.0f / GH)));
    const float g = gtab[gi];
    const float g2 = g * g;

    int ixlo = cidx(qx - g), ixhi = cidx(qx + g);
    int iylo = cidx(qy - g), iyhi = cidx(qy + g);
    int izlo = cidx(qz - g), izhi = cidx(qz + g);
    int nx = ixhi - ixlo + 1;
    int ny = iyhi - iylo + 1;
    int nyz = ny * (izhi - izlo + 1);
    const int lR  = (nyz >= 8) ? 3 : (nyz >= 4) ? 2 : (nyz >= 2) ? 1 : 0;
    const int R   = 1 << lR;
    const int lsl = 6 - lR;
    const unsigned SL = 64u >> lR;
    const unsigned slot = (unsigned)lane & (SL - 1u);
    unsigned cnt = 0;                          // wave-uniform by construction
    #pragma unroll 1
    for (int r0 = 0; r0 < nyz; r0 += 64) {
        int rr = r0 + lane;
        unsigned pk = 0;
        if (rr < nyz) {
            int iz = izlo + rr / ny;
            int iy = iylo + (rr - (rr / ny) * ny);
            int cb = (iz * NC + iy) * NC + ixlo;
            unsigned sB = cs[cb];
            pk = sB | ((cs[cb + nx] - sB) << 14);
        }
        int rmax = min(nyz - r0, 64);
        int gcount = (rmax + R - 1) >> lR;
        #pragma unroll 1
        for (int gg = 0; gg < gcount; ++gg) {
            unsigned pkm = __shfl(pk, (gg << lR) + (lane >> lsl), 64);
            unsigned sBm = pkm & 0x3FFFu;
            unsigned lm  = pkm >> 14;
            #pragma unroll 1
            for (unsigned st = slot; ; st += 2u * SL) {
                bool in0 = st < lm;
                if (!__any(in0 ? 1 : 0)) break;   // st>=lm all lanes => st+SL too
                unsigned st1 = st + SL;
                bool in1 = st1 < lm;
                float4 c0 = sp[min(sBm + st,  (unsigned)(NPTS - 1))];
                float4 c1 = sp[min(sBm + st1, (unsigned)(NPTS - 1))];
                float dx0 = qx - c0.x, dy0 = qy - c0.y, dz0 = qz - c0.z;
                float d20 = dx0 * dx0 + dy0 * dy0 + dz0 * dz0;
                float dx1 = qx - c1.x, dy1 = qy - c1.y, dz1 = qz - c1.z;
                float d21 = dx1 * dx1 + dy1 * dy1 + dz1 * dz1;
                bool p0 = in0 && (d20 < g2);
                bool p1 = in1 && (d21 < g2);
                unsigned long long m0 = __ballot(p0);
                unsigned long long m1 = __ballot(p1);
                if (p0) {
                    unsigned sw = min(cnt + mbcnt64(m0), (unsigned)(SSTRIDE - 1));
                    sl[sw] = mkkey(d20, __float_as_uint(c0.w));
                }
                unsigned cn = cnt + (unsigned)__popcll(m0);
                if (p1) {
                    unsigned sw = min(cn + mbcnt64(m1), (unsigned)(SSTRIDE - 1));
                    sl[sw] = mkkey(d21, __float_as_uint(c1.w));
                }
                cnt = cn + (unsigned)__popcll(m1);
            }
        }
    }

    // ---- in-wave top-16 via LDS rank-select (no dependent ballot chain) ----
    bool valid = (cnt >= KNN) && (cnt <= 128u);   // 2 keys/lane max
    if (valid) {
        unsigned k0 = (lane < (int)cnt)      ? sl[lane]      : 0xFFFFFFFFu;
        unsigned k1 = (lane + 64 < (int)cnt) ? sl[lane + 64] : 0xFFFFFFFFu;
        unsigned r0 = 0, r1 = 0;
        #pragma unroll 4
        for (unsigned m = 0; m < cnt; ++m) {
            unsigned km = sl[m];              // LDS broadcast (no conflict)
            r0 += (km < k0) ? 1u : 0u;
            r1 += (km < k1) ? 1u : 0u;
        }
        // P = 16th smallest = the key with rank 15 (exactly one; keys distinct)
        unsigned cand = 0;
        if (lane < (int)cnt && r0 == 15u) cand = k0;
        if (lane + 64 < (int)cnt && r1 == 15u) cand = k1;
        #pragma unroll
        for (int o = 1; o < 64; o <<= 1)
            cand = max(cand, (unsigned)__shfl_xor((int)cand, o, 64));
        // margin check: all filtered-out points provably outside 16th bucket
        float upper = __uint_as_float((cand & 0xFFFFE000u) + 0x2000u);
        valid = (upper < g2 * 0.999f - 1e-5f);
        if (valid) {
            if (lane < (int)cnt && r0 < 16u)
                idx16[(size_t)oq * 32 + r0] = k0 & 0x1FFFu;       // ascending
            if (lane + 64 < (int)cnt && r1 < 16u)
                idx16[(size_t)oq * 32 + r1] = k1 & 0x1FFFu;
        }
    }
    if (!valid && lane == 0) {       // exact fallback
        unsigned gl[KNN];
        #pragma unroll
        for (int m = 0; m < KNN; ++m) gl[m] = 0xFFFFFFFFu;
        #pragma unroll 1
        for (int i = 0; i < NPTS; ++i) {
            float cx = base[i * 3 + 0];
            float cy = base[i * 3 + 1];
            float cz = base[i * 3 + 2];
            float dx = qx - cx, dy = qy - cy, dz = qz - cz;
            float d2 = dx * dx + dy * dy + dz * dz;
            unsigned k = mkkey(d2, (unsigned)i);
            if (k < gl[KNN - 1]) insert16(k, gl);
        }
        unsigned* dst = idx16 + (size_t)oq * 32;
        #pragma unroll
        for (int m = 0; m < KNN; ++m) dst[m] = gl[m] & 0x1FFFu;
    }
}

// Patch kNN: 64 queries/block (quarter patch), 4 lanes/query x 64 patch pts,
// gated bubble insert + butterfly merge4 (verbatim).
__global__ void __launch_bounds__(256)
pselect_kernel(const float* __restrict__ pts, unsigned* __restrict__ idx16)
{
    __shared__ float4 pbuf4[PTCH];                 // 4 KB own patch
    const int t = threadIdx.x;
    const int w = t >> 6;
    const int lane = t & 63;
    const int p = blockIdx.x;
    const int quarter = blockIdx.y;
    const int b = blockIdx.z;
    const float* base = pts + (size_t)b * (NPTS * 3);

    {
        const float* src = base + p * (PTCH * 3);
        float* dst = (float*)pbuf4;
        #pragma unroll
        for (int s = 0; s < 3; ++s) {
            int f = t + s * 256;
            int j = f / 3;
            int c = f - 3 * j;
            dst[j * 4 + c] = src[f];
        }
    }
    __syncthreads();

    const int qq = lane >> 2;            // 0..15
    const int h = lane & 3;
    const int qlocal = quarter * 64 + w * 16 + qq;   // 0..255 within patch
    float4 qv = pbuf4[qlocal];
    const float pqx = qv.x, pqy = qv.y, pqz = qv.z;

    unsigned pl[KNN];
    #pragma unroll
    for (int m = 0; m < KNN; ++m) pl[m] = 0xFFFFFFFFu;
    const int j0 = h * 64;
    #pragma unroll 4
    for (int j = j0; j < j0 + 64; ++j) {
        float4 c = pbuf4[j];
        float dx = pqx - c.x, dy = pqy - c.y, dz = pqz - c.z;
        float d2 = dx * dx + dy * dy + dz * dz;
        unsigned k = mkkey(d2, (unsigned)j);
        if (k < pl[KNN - 1]) insert16(k, pl);
    }
    merge4(pl, lane);
    if (h == 0) {
        int qid = b * NPTS + p * PTCH + qlocal;
        unsigned* dst = idx16 + (size_t)qid * 32 + 16;   // type 1 = patch
        #pragma unroll
        for (int m = 0; m < KNN; ++m)
            dst[m] = (unsigned)(p * PTCH) + (pl[m] & 0x1FFFu);
    }
}

// 1 thread per eig (65536 = 32768 queries x {global,patch}); full-lane fp64.
__global__ void __launch_bounds__(256)
eig_loss_kernel(const float* __restrict__ pts,
                const unsigned* __restrict__ idx16,
                double* __restrict__ partials)
{
    __shared__ double sln[4], slv[4];
    const int t = threadIdx.x;
    const int e = blockIdx.x * 256 + t;     // 0..65535
    const int qid = e >> 1;
    const int b = qid >> 13;
    const int qi = qid & (NPTS - 1);
    const float* base = pts + (size_t)b * (NPTS * 3);

    const double qxd = (double)base[qi * 3 + 0];
    const double qyd = (double)base[qi * 3 + 1];
    const double qzd = (double)base[qi * 3 + 2];

    const unsigned* L = idx16 + (size_t)qid * 32 + (e & 1) * 16;
    double c00 = 0, c11 = 0, c22 = 0, c01 = 0, c02 = 0, c12 = 0;
    #pragma unroll
    for (int m = 0; m < KNN; ++m) {
        int idx = (int)L[m];
        double dx = (double)base[idx * 3 + 0] - qxd;
        double dy = (double)base[idx * 3 + 1] - qyd;
        double dz = (double)base[idx * 3 + 2] - qzd;
        c00 += dx * dx; c11 += dy * dy; c22 += dz * dz;
        c01 += dx * dy; c02 += dx * dz; c12 += dy * dz;
    }
    double nx, ny, nz, lmin, lsum;
    eig3(c00, c11, c22, c01, c02, c12, nx, ny, nz, lmin, lsum);
    double sv = lmin / lsum;

    double onx = __shfl_xor(nx, 1, 64);
    double ony = __shfl_xor(ny, 1, 64);
    double onz = __shfl_xor(nz, 1, 64);
    double osv = __shfl_xor(sv, 1, 64);

    double ln = 0.0, lsv = 0.0;
    if ((e & 1) == 0) {          // even lane: own = global, partner = patch
        double dx = fabs(onx) - fabs(nx);
        double dy = fabs(ony) - fabs(ny);
        double dz = fabs(onz) - fabs(nz);
        ln  = sqrt(dx * dx + dy * dy + dz * dz);
        double ds = osv - sv;
        lsv = ds * ds;
    }
    #pragma unroll
    for (int o = 32; o > 0; o >>= 1) {
        ln  += __shfl_down(ln, o);
        lsv += __shfl_down(lsv, o);
    }
    const int w = t >> 6;
    if ((t & 63) == 0) { sln[w] = ln; slv[w] = lsv; }
    __syncthreads();
    if (t == 0) {
        partials[blockIdx.x * 2 + 0] = sln[0] + sln[1] + sln[2] + sln[3];
        partials[blockIdx.x * 2 + 1] = slv[0] + slv[1] + slv[2] + slv[3];
    }
}

// 1 block: deterministic fixed-order double sum of 256 partial pairs.
__global__ void __launch_bounds__(256)
reduce_kernel(const double* __restrict__ partials, float* __restrict__ out)
{
    __shared__ double sln[4], slv[4];
    const int t = threadIdx.x;
    double a = partials[t * 2 + 0];
    double c = partials[t * 2 + 1];
    #pragma unroll
    for (int o = 32; o > 0; o >>= 1) {
        a += __shfl_down(a, o);
        c += __shfl_down(c, o);
    }
    if ((t & 63) == 0) { sln[t >> 6] = a; slv[t >> 6] = c; }
    __syncthreads();
    if (t == 0) {
        const double inv = 1.0 / (double)(NBATCH * NPTS);
        out[0] = (float)((sln[0] + sln[1] + sln[2] + sln[3]) * inv);
        out[1] = (float)((slv[0] + slv[1] + slv[2] + slv[3]) * inv);
    }
}

extern "C" void kernel_launch(void* const* d_in, const int* in_sizes, int n_in,
                              void* d_out, int out_size, void* d_ws, size_t ws_size,
                              hipStream_t stream)
{
    const float* pts = (const float*)d_in[0];
    float* out = (float*)d_out;

    // workspace carve-up (16B-aligned), ~4.8 MB total:
    //   cellStart @ 0       : 4*4097*4   = 65552
    //   sorted    @ 65552   : 4*8192*16  = 524288  -> 589840
    //   gtab      @ 589840  : 512*4      = 2048    -> 591888
    //   idx16     @ 591888  : 32768*32*4 = 4194304 -> 4786192
    //   partials  @ 4786192 : 256*2*8    = 4096    -> 4790288
    unsigned char* ws = (unsigned char*)d_ws;
    unsigned* cellStart = (unsigned*)(ws);
    float4*   sorted    = (float4*)  (ws + 65552);
    float*    gtab      = (float*)   (ws + 589840);
    unsigned* idx16     = (unsigned*)(ws + 591888);
    double*   partials  = (double*)  (ws + 4786192);

    hipLaunchKernelGGL(build_kernel, dim3(NBATCH), dim3(BT), 0, stream,
                       pts, cellStart, sorted, gtab);
    hipLaunchKernelGGL(fselect_kernel, dim3(NBATCH * NPTS / 4), dim3(256), 0, stream,
                       pts, cellStart, sorted, gtab, idx16);
    hipLaunchKernelGGL(pselect_kernel, dim3(NPATCH, 4, NBATCH), dim3(256), 0, stream,
                       pts, idx16);
    hipLaunchKernelGGL(eig_loss_kernel, dim3(NBATCH * NPTS * 2 / 256), dim3(256),
                       0, stream, pts, idx16, partials);
    hipLaunchKernelGGL(reduce_kernel, dim3(1), dim3(256), 0, stream,
                       partials, out);
}